// Round 4
// baseline (459.511 us; speedup 1.0000x reference)
//
#include <hip/hip_runtime.h>
#include <hip/hip_bf16.h>
#include <stdint.h>

#define NN 100000
#define NE 1600000
#define DD 128
#define NBLK 98        // ceil(NN/1024) for the row scan
#define NBKT 8         // row megabuckets
#define RPB 12500      // rows per megabucket
#define NSHARD 32      // cursor shards per bucket
#define SCAP 7040      // capacity per (bucket,shard): mean 6250, +10.7 sigma

typedef __attribute__((ext_vector_type(8))) short short8;  // 8 bf16 (4 VGPRs)
typedef __attribute__((ext_vector_type(4))) float f32x4;   // MFMA C/D frag

__device__ inline unsigned bf16bits(float x) {
  __hip_bfloat16 h = __float2bfloat16(x);
  return (unsigned)*reinterpret_cast<unsigned short*>(&h);
}

__device__ inline float bfhi(unsigned u) { return __uint_as_float(u & 0xffff0000u); }
__device__ inline float bflo(unsigned u) { return __uint_as_float(u << 16); }

// ---------------- emb -> bf16 table (+ shard-cursor init) ----------------
__global__ __launch_bounds__(256) void k_cvt(const float* __restrict__ emb,
                                             uint4* __restrict__ tbl,
                                             int* __restrict__ mbcur) {
  int i = blockIdx.x * 256 + threadIdx.x;
  if (blockIdx.x == 0 && threadIdx.x < NBKT * NSHARD)
    mbcur[threadIdx.x] = threadIdx.x * SCAP;
  const float4 a = ((const float4*)emb)[2 * i];
  const float4 b = ((const float4*)emb)[2 * i + 1];
  uint4 u;
  u.x = bf16bits(a.x) | (bf16bits(a.y) << 16);
  u.y = bf16bits(a.z) | (bf16bits(a.w) << 16);
  u.z = bf16bits(b.x) | (bf16bits(b.y) << 16);
  u.w = bf16bits(b.z) | (bf16bits(b.w) << 16);
  tbl[i] = u;
}

// ---------------- partition edges into 8 megabuckets (ballot-aggregated) ---
// ebuf entry: .x = (col<<15)|q15(val), .y = row
__global__ __launch_bounds__(256) void k_bscatter(
    const int* __restrict__ row, const int* __restrict__ col,
    const float* __restrict__ val, int* __restrict__ mbcur,
    uint2* __restrict__ ebuf) {
  const int lane = threadIdx.x & 63;
  const int shard = ((blockIdx.x << 2) | (threadIdx.x >> 6)) & (NSHARD - 1);
  const unsigned long long lmask = (1ull << lane) - 1ull;  // bits below lane
  int stride = gridDim.x * 256;
  for (int i = blockIdx.x * 256 + threadIdx.x; i < NE; i += stride) {
    int r = row[i];
    unsigned pk = ((unsigned)col[i] << 15) |
                  (unsigned)__float2int_rn(val[i] * 32767.0f);
    int m = r / RPB;
#pragma unroll
    for (int b = 0; b < NBKT; ++b) {
      unsigned long long mask = __ballot(m == b);
      if (mask == 0ull) continue;
      int leader = (int)__builtin_ctzll(mask);
      int cnt = (int)__popcll(mask);
      int pbase = 0;
      if (lane == leader) pbase = atomicAdd(&mbcur[b * NSHARD + shard], cnt);
      pbase = __shfl(pbase, leader, 64);
      if (m == b) {
        int rank = (int)__popcll(mask & lmask);
        ebuf[pbase + rank] = make_uint2(pk, (unsigned)r);
      }
    }
  }
}

// ---------------- per-(bucket,chunk) LDS histogram ----------------
// block b: m = b&7 (XCD pin), c = b>>3; chunk c covers shards 4c..4c+3
__global__ __launch_bounds__(1024) void k_hist(const uint2* __restrict__ ebuf,
                                               const int* __restrict__ mbcur,
                                               int* __restrict__ partial) {
  __shared__ int h[RPB];  // 50 KB
  const int m = blockIdx.x & 7, c = blockIdx.x >> 3;
  for (int i = threadIdx.x; i < RPB; i += 1024) h[i] = 0;
  __syncthreads();
  const int base = m * RPB;
#pragma unroll
  for (int s4 = 0; s4 < 4; ++s4) {
    int ms = m * NSHARD + c * 4 + s4;
    int sbase = ms * SCAP;
    int scnt = mbcur[ms] - sbase;
    const uint2* src = ebuf + sbase;
    for (int i = threadIdx.x; i < scnt; i += 1024)
      atomicAdd(&h[(int)src[i].y - base], 1);
  }
  __syncthreads();
  int* dst = partial + (m * 8 + c) * RPB;
  for (int i = threadIdx.x; i < RPB; i += 1024) dst[i] = h[i];
}

// ---------------- per-row chunk prefix + totals ----------------
__global__ void k_sum(int* __restrict__ partial, int* __restrict__ counts) {
  int r = blockIdx.x * 256 + threadIdx.x;
  if (r >= NN) return;
  int m = r / RPB, rl = r - m * RPB;
  int* p = partial + m * 8 * RPB + rl;
  int s = 0;
#pragma unroll
  for (int cc = 0; cc < 8; ++cc) {
    int v = p[cc * RPB];
    p[cc * RPB] = s;  // chunk-exclusive prefix
    s += v;
  }
  counts[r] = s;
}

// ---------------- hierarchical exclusive scan over row counts ----------------
__global__ __launch_bounds__(1024) void k_scan1(const int* __restrict__ counts,
                                                int* __restrict__ offsets,
                                                int* __restrict__ bsum) {
  __shared__ int wsum[16];
  const int t = threadIdx.x, lane = t & 63, wid = t >> 6;
  int i = blockIdx.x * 1024 + t;
  int v = (i < NN) ? counts[i] : 0;
  int incl = v;
#pragma unroll
  for (int d = 1; d < 64; d <<= 1) {
    int u = __shfl_up(incl, d, 64);
    if (lane >= d) incl += u;
  }
  if (lane == 63) wsum[wid] = incl;
  __syncthreads();
  if (wid == 0) {
    int w = (lane < 16) ? wsum[lane] : 0;
#pragma unroll
    for (int d = 1; d < 16; d <<= 1) {
      int u = __shfl_up(w, d, 64);
      if (lane >= d) w += u;
    }
    if (lane < 16) wsum[lane] = w;
  }
  __syncthreads();
  int wbase = wid ? wsum[wid - 1] : 0;
  if (i < NN) offsets[i] = wbase + incl - v;
  if (t == 0) bsum[blockIdx.x] = wsum[15];
}

__global__ void k_scan2(const int* __restrict__ bsum, int* __restrict__ bpre) {
  const int lane = threadIdx.x;  // 64 threads
  int a = bsum[lane];
  int b = (lane + 64 < NBLK) ? bsum[lane + 64] : 0;
  int sa = a, sb = b;
#pragma unroll
  for (int d = 1; d < 64; d <<= 1) {
    int u = __shfl_up(sa, d, 64);
    if (lane >= d) sa += u;
    u = __shfl_up(sb, d, 64);
    if (lane >= d) sb += u;
  }
  int totA = __shfl(sa, 63, 64);
  bpre[lane] = sa - a;
  if (lane + 64 < NBLK) bpre[lane + 64] = totA + sb - b;
}

__global__ __launch_bounds__(1024) void k_scan3(int* __restrict__ offsets,
                                                const int* __restrict__ bpre) {
  int i = blockIdx.x * 1024 + threadIdx.x;
  if (i < NN) offsets[i] += bpre[blockIdx.x];
  if (i == 0) offsets[NN] = NE;
}

// ---------------- CSR scatter with LDS cursors (zero global atomics) -------
__global__ __launch_bounds__(1024) void k_scatter3(
    const uint2* __restrict__ ebuf, const int* __restrict__ mbcur,
    const int* __restrict__ partial, const int* __restrict__ offsets,
    unsigned* __restrict__ cpack) {
  __shared__ int cur[RPB];  // 50 KB
  const int m = blockIdx.x & 7, c = blockIdx.x >> 3;
  const int base = m * RPB;
  const int* pre = partial + (m * 8 + c) * RPB;
  for (int i = threadIdx.x; i < RPB; i += 1024)
    cur[i] = offsets[base + i] + pre[i];
  __syncthreads();
#pragma unroll
  for (int s4 = 0; s4 < 4; ++s4) {
    int ms = m * NSHARD + c * 4 + s4;
    int sbase = ms * SCAP;
    int scnt = mbcur[ms] - sbase;
    const uint2* src = ebuf + sbase;
    for (int i = threadIdx.x; i < scnt; i += 1024) {
      uint2 e = src[i];
      int pos = atomicAdd(&cur[(int)e.y - base], 1);  // LDS atomic
      cpack[pos] = e.x;
    }
  }
}

// ---------------- SpMM, one wave per node, bf16 gathers ----------------
__global__ __launch_bounds__(256) void k_spmm(
    const int* __restrict__ offsets, const unsigned* __restrict__ cpack,
    const unsigned short* __restrict__ tbl, unsigned* __restrict__ rel) {
  const int lane = threadIdx.x & 63;
  const int node = blockIdx.x * 4 + (threadIdx.x >> 6);
  if (node >= NN) return;
  const int beg = offsets[node], end = offsets[node + 1];
  float ax = 0.f, ay = 0.f;
  for (int j0 = beg; j0 < end; j0 += 64) {
    int idx = j0 + lane;
    unsigned pk = (idx < end) ? cpack[idx] : 0u;  // coalesced; 0 => c=0,v=0
    int n4 = (min(end - j0, 64) + 3) & ~3;
    for (int t = 0; t < n4; t += 4) {
#pragma unroll
      for (int s = 0; s < 4; ++s) {  // 4 independent gathers in flight
        unsigned u = (unsigned)__shfl((int)pk, t + s, 64);
        unsigned c = u >> 15;
        float v = (float)(u & 32767u) * (1.0f / 32767.0f);
        unsigned w = *(const unsigned*)(tbl + ((size_t)c << 7) + (lane << 1));
        ax = fmaf(v, bflo(w), ax);
        ay = fmaf(v, bfhi(w), ay);
      }
    }
  }
  rel[(size_t)node * 64 + lane] = bf16bits(ax) | (bf16bits(ay) << 16);
}

// ---------------- W pack: B-fragment layout for MFMA ----------------
__global__ void k_packw(const float* __restrict__ W1, const float* __restrict__ W2,
                        uint4* __restrict__ wpack) {
  int cid = blockIdx.x * 256 + threadIdx.x;
  if (cid >= 4096) return;
  int lane = cid & 63, ct = (cid >> 6) & 7, ks = cid >> 9;
  int colc = ct * 16 + (lane & 15);
  int k0 = ks * 32 + (lane >> 4) * 8;
  unsigned h[8];
#pragma unroll
  for (int j = 0; j < 8; ++j) {
    int kk = k0 + j;
    float w = (kk < DD) ? W1[kk * DD + colc] : W2[(kk - DD) * DD + colc];
    h[j] = bf16bits(w);
  }
  uint4 u;
  u.x = h[0] | (h[1] << 16);
  u.y = h[2] | (h[3] << 16);
  u.z = h[4] | (h[5] << 16);
  u.w = h[6] | (h[7] << 16);
  wpack[cid] = u;
}

// elementwise bf16 product of two 8-wide bf16 frags
__device__ inline short8 bfmul8(short8 a, short8 b) {
  short8 r;
#pragma unroll
  for (int i = 0; i < 8; ++i) {
    float fa = __uint_as_float(((unsigned)(unsigned short)a[i]) << 16);
    float fb = __uint_as_float(((unsigned)(unsigned short)b[i]) << 16);
    r[i] = (short)bf16bits(fa * fb);
  }
  return r;
}

// ---------------- Phase 2: out = rel@W1 + (rel.*emb)@W2, MFMA -------------
__global__ __launch_bounds__(256) void k_phase2(
    const unsigned short* __restrict__ rel, const unsigned short* __restrict__ tbl,
    const uint4* __restrict__ wpack, float* __restrict__ out) {
  __shared__ uint4 bw[4096];  // 64 KiB: B frags [ks(8)][ct(8)][lane(64)]
  for (int i = threadIdx.x; i < 4096; i += 256) bw[i] = wpack[i];
  __syncthreads();

  const int lane = threadIdx.x & 63;
  const int wid = threadIdx.x >> 6;
  const long Rw = (long)blockIdx.x * 128 + wid * 32;

  long r0 = Rw + (lane & 15);
  long r1 = r0 + 16;
  if (r0 >= NN) r0 = NN - 1;
  if (r1 >= NN) r1 = NN - 1;
  const int fo = (lane >> 4) * 8;

  f32x4 acc[2][8] = {};

#pragma unroll
  for (int ks = 0; ks < 4; ++ks) {
    short8 rf0 = *(const short8*)(rel + r0 * DD + ks * 32 + fo);
    short8 ef0 = *(const short8*)(tbl + r0 * DD + ks * 32 + fo);
    short8 rf1 = *(const short8*)(rel + r1 * DD + ks * 32 + fo);
    short8 ef1 = *(const short8*)(tbl + r1 * DD + ks * 32 + fo);
    short8 m0 = bfmul8(rf0, ef0);
    short8 m1 = bfmul8(rf1, ef1);
#pragma unroll
    for (int ct = 0; ct < 8; ++ct) {
      short8 b1 = *(const short8*)&bw[(ks * 8 + ct) * 64 + lane];
      short8 b2 = *(const short8*)&bw[((ks + 4) * 8 + ct) * 64 + lane];
      acc[0][ct] = __builtin_amdgcn_mfma_f32_16x16x32_bf16(rf0, b1, acc[0][ct], 0, 0, 0);
      acc[0][ct] = __builtin_amdgcn_mfma_f32_16x16x32_bf16(m0, b2, acc[0][ct], 0, 0, 0);
      acc[1][ct] = __builtin_amdgcn_mfma_f32_16x16x32_bf16(rf1, b1, acc[1][ct], 0, 0, 0);
      acc[1][ct] = __builtin_amdgcn_mfma_f32_16x16x32_bf16(m1, b2, acc[1][ct], 0, 0, 0);
    }
  }

  const int orow = (lane >> 4) * 4;
  const int ocol = lane & 15;
#pragma unroll
  for (int rt = 0; rt < 2; ++rt) {
    long rbase = Rw + rt * 16 + orow;
#pragma unroll
    for (int ct = 0; ct < 8; ++ct) {
#pragma unroll
      for (int q = 0; q < 4; ++q) {
        long rr = rbase + q;
        if (rr < NN) out[rr * DD + ct * 16 + ocol] = acc[rt][ct][q];
      }
    }
  }
}

extern "C" void kernel_launch(void* const* d_in, const int* in_sizes, int n_in,
                              void* d_out, int out_size, void* d_ws, size_t ws_size,
                              hipStream_t stream) {
  const float* emb = (const float*)d_in[0];
  const int* erow = (const int*)d_in[1];
  const int* ecol = (const int*)d_in[2];
  const float* eva = (const float*)d_in[3];
  const float* W1 = (const float*)d_in[4];
  const float* W2 = (const float*)d_in[5];
  float* out = (float*)d_out;

  // workspace layout (bytes), total 58,466,688 (same as proven):
  //   tbl     @ 0          : 25,600,000  (bf16 emb)
  //   rel     @ 25,600,000 : 25,600,000  (bf16 rel; scratch until k_spmm:)
  //     ebuf    = rel+0          : 14,417,920 (8*32*7040 uint2)
  //     partial = rel+14,417,920 :  3,200,000 (8*8*12500 int)
  //     mbcur   = rel+17,617,920 :      1,024 (256 int shard cursors)
  //   offsets @ 51,200,000 : 400,128
  //   counts  @ 51,600,128 : 400,000
  //   cpack   @ 52,000,128 : 6,400,000
  //   bsum    @ 58,400,128 : 512
  //   bpre    @ 58,400,640 : 512
  //   wpack   @ 58,401,152 : 65,536
  char* ws = (char*)d_ws;
  unsigned short* tbl = (unsigned short*)(ws);
  unsigned short* rel = (unsigned short*)(ws + 25600000);
  uint2* ebuf = (uint2*)(ws + 25600000);
  int* partial = (int*)(ws + 25600000 + 14417920);
  int* mbcur = (int*)(ws + 25600000 + 17617920);
  int* offsets = (int*)(ws + 51200000);
  int* counts = (int*)(ws + 51600128);
  unsigned* cpack = (unsigned*)(ws + 52000128);
  int* bsum = (int*)(ws + 58400128);
  int* bpre = (int*)(ws + 58400640);
  uint4* wpack = (uint4*)(ws + 58401152);

  k_cvt<<<6250, 256, 0, stream>>>(emb, (uint4*)tbl, mbcur);
  k_bscatter<<<1024, 256, 0, stream>>>(erow, ecol, eva, mbcur, ebuf);
  k_hist<<<64, 1024, 0, stream>>>(ebuf, mbcur, partial);
  k_sum<<<(NN + 255) / 256, 256, 0, stream>>>(partial, counts);
  k_scan1<<<NBLK, 1024, 0, stream>>>(counts, offsets, bsum);
  k_scan2<<<1, 64, 0, stream>>>(bsum, bpre);
  k_scan3<<<NBLK, 1024, 0, stream>>>(offsets, bpre);
  k_scatter3<<<64, 1024, 0, stream>>>(ebuf, mbcur, partial, offsets, cpack);
  k_packw<<<16, 256, 0, stream>>>(W1, W2, wpack);
  k_spmm<<<NN / 4, 256, 0, stream>>>(offsets, cpack, tbl, (unsigned*)rel);
  k_phase2<<<(NN + 127) / 128, 256, 0, stream>>>(rel, tbl, wpack, out);
}

// Round 5
// 183.515 us; speedup vs baseline: 2.5039x; 2.5039x over previous
//
#include <hip/hip_runtime.h>
#include <hip/hip_bf16.h>
#include <stdint.h>

#define NN 100000
#define NE 1600000
#define DD 128
#define NBLK 98        // ceil(NN/1024) for the row scan
#define NBKT 8         // row megabuckets
#define RPB 12500      // rows per megabucket
#define NSHARD 32      // cursor shards per bucket
#define SCAP 7040      // capacity per (bucket,shard): mean 6250, sigma ~74
#define PBLK 512       // partition blocks
#define PTHR 512       // partition threads/block
#define PCHUNK 3125    // NE / PBLK

typedef __attribute__((ext_vector_type(8))) short short8;  // 8 bf16 (4 VGPRs)
typedef __attribute__((ext_vector_type(4))) float f32x4;   // MFMA C/D frag

__device__ inline unsigned bf16bits(float x) {
  __hip_bfloat16 h = __float2bfloat16(x);
  return (unsigned)*reinterpret_cast<unsigned short*>(&h);
}

__device__ inline float bfhi(unsigned u) { return __uint_as_float(u & 0xffff0000u); }
__device__ inline float bflo(unsigned u) { return __uint_as_float(u << 16); }

// ---------------- emb -> bf16 table (+ shard-cursor init) ----------------
__global__ __launch_bounds__(256) void k_cvt(const float* __restrict__ emb,
                                             uint4* __restrict__ tbl,
                                             int* __restrict__ mbcur) {
  int i = blockIdx.x * 256 + threadIdx.x;
  if (blockIdx.x == 0 && threadIdx.x < NBKT * NSHARD)
    mbcur[threadIdx.x] = threadIdx.x * SCAP;
  const float4 a = ((const float4*)emb)[2 * i];
  const float4 b = ((const float4*)emb)[2 * i + 1];
  uint4 u;
  u.x = bf16bits(a.x) | (bf16bits(a.y) << 16);
  u.y = bf16bits(a.z) | (bf16bits(a.w) << 16);
  u.z = bf16bits(b.x) | (bf16bits(b.y) << 16);
  u.w = bf16bits(b.z) | (bf16bits(b.w) << 16);
  tbl[i] = u;
}

// ---------------- partition edges into 8 megabuckets (LDS-staged) ----------
// ebuf entry: .x = (col<<15)|q15(val), .y = row
// shard = blockIdx&31; shard&7 == blockIdx&7 -> cursor + segment XCD-local.
__global__ __launch_bounds__(512) void k_bscatter2(
    const int* __restrict__ row, const int* __restrict__ col,
    const float* __restrict__ val, int* __restrict__ mbcur,
    uint2* __restrict__ ebuf) {
  __shared__ uint2 buf[NBKT][PTHR];  // 32 KB staging
  __shared__ int lcnt[NBKT];
  __shared__ int gbase[NBKT];
  const int t = threadIdx.x;
  const int shard = blockIdx.x & (NSHARD - 1);
  if (t < NBKT) lcnt[t] = 0;
  __syncthreads();
  const int e0 = blockIdx.x * PCHUNK;
  for (int base = 0; base < PCHUNK; base += PTHR) {
    const bool have = (base + t) < PCHUNK;
    if (have) {
      int i = e0 + base + t;
      int r = row[i];
      int m = r / RPB;
      uint2 e;
      e.x = ((unsigned)col[i] << 15) |
            (unsigned)__float2int_rn(val[i] * 32767.0f);
      e.y = (unsigned)r;
      int idx = atomicAdd(&lcnt[m], 1);  // LDS atomic; idx < PTHR == CAP
      buf[m][idx] = e;
    }
    __syncthreads();
    if (t < NBKT)
      gbase[t] = atomicAdd(&mbcur[t * NSHARD + shard], lcnt[t]);
    __syncthreads();
#pragma unroll
    for (int b = 0; b < NBKT; ++b) {  // cooperative coalesced flush
      int c = lcnt[b];
      uint2* dst = ebuf + gbase[b];
      for (int k = t; k < c; k += PTHR) dst[k] = buf[b][k];
    }
    __syncthreads();
    if (t < NBKT) lcnt[t] = 0;
    __syncthreads();
  }
}

// ---------------- per-(bucket,chunk) LDS histogram ----------------
// block b: m = b&7 (XCD pin), c = b>>3; chunk c covers shards 4c..4c+3
__global__ __launch_bounds__(1024) void k_hist(const uint2* __restrict__ ebuf,
                                               const int* __restrict__ mbcur,
                                               int* __restrict__ partial) {
  __shared__ int h[RPB];  // 50 KB
  const int m = blockIdx.x & 7, c = blockIdx.x >> 3;
  for (int i = threadIdx.x; i < RPB; i += 1024) h[i] = 0;
  __syncthreads();
  const int base = m * RPB;
#pragma unroll
  for (int s4 = 0; s4 < 4; ++s4) {
    int ms = m * NSHARD + c * 4 + s4;
    int sbase = ms * SCAP;
    int scnt = mbcur[ms] - sbase;
    const uint2* src = ebuf + sbase;
    for (int i = threadIdx.x; i < scnt; i += 1024)
      atomicAdd(&h[(int)src[i].y - base], 1);
  }
  __syncthreads();
  int* dst = partial + (m * 8 + c) * RPB;
  for (int i = threadIdx.x; i < RPB; i += 1024) dst[i] = h[i];
}

// ---------------- per-row chunk prefix + totals ----------------
__global__ void k_sum(int* __restrict__ partial, int* __restrict__ counts) {
  int r = blockIdx.x * 256 + threadIdx.x;
  if (r >= NN) return;
  int m = r / RPB, rl = r - m * RPB;
  int* p = partial + m * 8 * RPB + rl;
  int s = 0;
#pragma unroll
  for (int cc = 0; cc < 8; ++cc) {
    int v = p[cc * RPB];
    p[cc * RPB] = s;  // chunk-exclusive prefix
    s += v;
  }
  counts[r] = s;
}

// ---------------- hierarchical exclusive scan over row counts --------------
__global__ __launch_bounds__(1024) void k_scan1(const int* __restrict__ counts,
                                                int* __restrict__ offsets,
                                                int* __restrict__ bsum) {
  __shared__ int wsum[16];
  const int t = threadIdx.x, lane = t & 63, wid = t >> 6;
  int i = blockIdx.x * 1024 + t;
  int v = (i < NN) ? counts[i] : 0;
  int incl = v;
#pragma unroll
  for (int d = 1; d < 64; d <<= 1) {
    int u = __shfl_up(incl, d, 64);
    if (lane >= d) incl += u;
  }
  if (lane == 63) wsum[wid] = incl;
  __syncthreads();
  if (wid == 0) {
    int w = (lane < 16) ? wsum[lane] : 0;
#pragma unroll
    for (int d = 1; d < 16; d <<= 1) {
      int u = __shfl_up(w, d, 64);
      if (lane >= d) w += u;
    }
    if (lane < 16) wsum[lane] = w;
  }
  __syncthreads();
  int wbase = wid ? wsum[wid - 1] : 0;
  if (i < NN) offsets[i] = wbase + incl - v;
  if (t == 0) bsum[blockIdx.x] = wsum[15];
}

__global__ void k_scan2(const int* __restrict__ bsum, int* __restrict__ bpre) {
  const int lane = threadIdx.x;  // 64 threads
  int a = bsum[lane];
  int b = (lane + 64 < NBLK) ? bsum[lane + 64] : 0;
  int sa = a, sb = b;
#pragma unroll
  for (int d = 1; d < 64; d <<= 1) {
    int u = __shfl_up(sa, d, 64);
    if (lane >= d) sa += u;
    u = __shfl_up(sb, d, 64);
    if (lane >= d) sb += u;
  }
  int totA = __shfl(sa, 63, 64);
  bpre[lane] = sa - a;
  if (lane + 64 < NBLK) bpre[lane + 64] = totA + sb - b;
}

__global__ __launch_bounds__(1024) void k_scan3(int* __restrict__ offsets,
                                                const int* __restrict__ bpre) {
  int i = blockIdx.x * 1024 + threadIdx.x;
  if (i < NN) offsets[i] += bpre[blockIdx.x];
  if (i == 0) offsets[NN] = NE;
}

// ---------------- CSR scatter with LDS cursors (zero global atomics) -------
__global__ __launch_bounds__(1024) void k_scatter3(
    const uint2* __restrict__ ebuf, const int* __restrict__ mbcur,
    const int* __restrict__ partial, const int* __restrict__ offsets,
    unsigned* __restrict__ cpack) {
  __shared__ int cur[RPB];  // 50 KB
  const int m = blockIdx.x & 7, c = blockIdx.x >> 3;
  const int base = m * RPB;
  const int* pre = partial + (m * 8 + c) * RPB;
  for (int i = threadIdx.x; i < RPB; i += 1024)
    cur[i] = offsets[base + i] + pre[i];
  __syncthreads();
#pragma unroll
  for (int s4 = 0; s4 < 4; ++s4) {
    int ms = m * NSHARD + c * 4 + s4;
    int sbase = ms * SCAP;
    int scnt = mbcur[ms] - sbase;
    const uint2* src = ebuf + sbase;
    for (int i = threadIdx.x; i < scnt; i += 1024) {
      uint2 e = src[i];
      int pos = atomicAdd(&cur[(int)e.y - base], 1);  // LDS atomic
      cpack[pos] = e.x;
    }
  }
}

// ---------------- SpMM, one wave per node, bf16 gathers ----------------
__global__ __launch_bounds__(256) void k_spmm(
    const int* __restrict__ offsets, const unsigned* __restrict__ cpack,
    const unsigned short* __restrict__ tbl, unsigned* __restrict__ rel) {
  const int lane = threadIdx.x & 63;
  const int node = blockIdx.x * 4 + (threadIdx.x >> 6);
  if (node >= NN) return;
  const int beg = offsets[node], end = offsets[node + 1];
  float ax = 0.f, ay = 0.f;
  for (int j0 = beg; j0 < end; j0 += 64) {
    int idx = j0 + lane;
    unsigned pk = (idx < end) ? cpack[idx] : 0u;  // coalesced; 0 => c=0,v=0
    int n8 = (min(end - j0, 64) + 7) & ~7;
    for (int t = 0; t < n8; t += 8) {
#pragma unroll
      for (int s = 0; s < 8; ++s) {  // 8 independent gathers in flight
        unsigned u = (unsigned)__shfl((int)pk, t + s, 64);
        unsigned c = u >> 15;
        float v = (float)(u & 32767u) * (1.0f / 32767.0f);
        unsigned w = *(const unsigned*)(tbl + ((size_t)c << 7) + (lane << 1));
        ax = fmaf(v, bflo(w), ax);
        ay = fmaf(v, bfhi(w), ay);
      }
    }
  }
  rel[(size_t)node * 64 + lane] = bf16bits(ax) | (bf16bits(ay) << 16);
}

// ---------------- W pack: B-fragment layout for MFMA ----------------
__global__ void k_packw(const float* __restrict__ W1, const float* __restrict__ W2,
                        uint4* __restrict__ wpack) {
  int cid = blockIdx.x * 256 + threadIdx.x;
  if (cid >= 4096) return;
  int lane = cid & 63, ct = (cid >> 6) & 7, ks = cid >> 9;
  int colc = ct * 16 + (lane & 15);
  int k0 = ks * 32 + (lane >> 4) * 8;
  unsigned h[8];
#pragma unroll
  for (int j = 0; j < 8; ++j) {
    int kk = k0 + j;
    float w = (kk < DD) ? W1[kk * DD + colc] : W2[(kk - DD) * DD + colc];
    h[j] = bf16bits(w);
  }
  uint4 u;
  u.x = h[0] | (h[1] << 16);
  u.y = h[2] | (h[3] << 16);
  u.z = h[4] | (h[5] << 16);
  u.w = h[6] | (h[7] << 16);
  wpack[cid] = u;
}

// elementwise bf16 product of two 8-wide bf16 frags
__device__ inline short8 bfmul8(short8 a, short8 b) {
  short8 r;
#pragma unroll
  for (int i = 0; i < 8; ++i) {
    float fa = __uint_as_float(((unsigned)(unsigned short)a[i]) << 16);
    float fb = __uint_as_float(((unsigned)(unsigned short)b[i]) << 16);
    r[i] = (short)bf16bits(fa * fb);
  }
  return r;
}

// ---------------- Phase 2: out = rel@W1 + (rel.*emb)@W2, MFMA -------------
__global__ __launch_bounds__(256) void k_phase2(
    const unsigned short* __restrict__ rel, const unsigned short* __restrict__ tbl,
    const uint4* __restrict__ wpack, float* __restrict__ out) {
  __shared__ uint4 bw[4096];  // 64 KiB: B frags [ks(8)][ct(8)][lane(64)]
  for (int i = threadIdx.x; i < 4096; i += 256) bw[i] = wpack[i];
  __syncthreads();

  const int lane = threadIdx.x & 63;
  const int wid = threadIdx.x >> 6;
  const long Rw = (long)blockIdx.x * 128 + wid * 32;

  long r0 = Rw + (lane & 15);
  long r1 = r0 + 16;
  if (r0 >= NN) r0 = NN - 1;
  if (r1 >= NN) r1 = NN - 1;
  const int fo = (lane >> 4) * 8;

  f32x4 acc[2][8] = {};

#pragma unroll
  for (int ks = 0; ks < 4; ++ks) {
    short8 rf0 = *(const short8*)(rel + r0 * DD + ks * 32 + fo);
    short8 ef0 = *(const short8*)(tbl + r0 * DD + ks * 32 + fo);
    short8 rf1 = *(const short8*)(rel + r1 * DD + ks * 32 + fo);
    short8 ef1 = *(const short8*)(tbl + r1 * DD + ks * 32 + fo);
    short8 m0 = bfmul8(rf0, ef0);
    short8 m1 = bfmul8(rf1, ef1);
#pragma unroll
    for (int ct = 0; ct < 8; ++ct) {
      short8 b1 = *(const short8*)&bw[(ks * 8 + ct) * 64 + lane];
      short8 b2 = *(const short8*)&bw[((ks + 4) * 8 + ct) * 64 + lane];
      acc[0][ct] = __builtin_amdgcn_mfma_f32_16x16x32_bf16(rf0, b1, acc[0][ct], 0, 0, 0);
      acc[0][ct] = __builtin_amdgcn_mfma_f32_16x16x32_bf16(m0, b2, acc[0][ct], 0, 0, 0);
      acc[1][ct] = __builtin_amdgcn_mfma_f32_16x16x32_bf16(rf1, b1, acc[1][ct], 0, 0, 0);
      acc[1][ct] = __builtin_amdgcn_mfma_f32_16x16x32_bf16(m1, b2, acc[1][ct], 0, 0, 0);
    }
  }

  const int orow = (lane >> 4) * 4;
  const int ocol = lane & 15;
#pragma unroll
  for (int rt = 0; rt < 2; ++rt) {
    long rbase = Rw + rt * 16 + orow;
#pragma unroll
    for (int ct = 0; ct < 8; ++ct) {
#pragma unroll
      for (int q = 0; q < 4; ++q) {
        long rr = rbase + q;
        if (rr < NN) out[rr * DD + ct * 16 + ocol] = acc[rt][ct][q];
      }
    }
  }
}

extern "C" void kernel_launch(void* const* d_in, const int* in_sizes, int n_in,
                              void* d_out, int out_size, void* d_ws, size_t ws_size,
                              hipStream_t stream) {
  const float* emb = (const float*)d_in[0];
  const int* erow = (const int*)d_in[1];
  const int* ecol = (const int*)d_in[2];
  const float* eva = (const float*)d_in[3];
  const float* W1 = (const float*)d_in[4];
  const float* W2 = (const float*)d_in[5];
  float* out = (float*)d_out;

  // workspace layout (bytes), total 58,466,688 (same as proven):
  //   tbl     @ 0          : 25,600,000  (bf16 emb)
  //   rel     @ 25,600,000 : 25,600,000  (bf16 rel; scratch until k_spmm:)
  //     ebuf    = rel+0          : 14,417,920 (8*32*7040 uint2)
  //     partial = rel+14,417,920 :  3,200,000 (8*8*12500 int)
  //     mbcur   = rel+17,617,920 :      1,024 (256 int shard cursors)
  //   offsets @ 51,200,000 : 400,128
  //   counts  @ 51,600,128 : 400,000
  //   cpack   @ 52,000,128 : 6,400,000
  //   bsum    @ 58,400,128 : 512
  //   bpre    @ 58,400,640 : 512
  //   wpack   @ 58,401,152 : 65,536
  char* ws = (char*)d_ws;
  unsigned short* tbl = (unsigned short*)(ws);
  unsigned short* rel = (unsigned short*)(ws + 25600000);
  uint2* ebuf = (uint2*)(ws + 25600000);
  int* partial = (int*)(ws + 25600000 + 14417920);
  int* mbcur = (int*)(ws + 25600000 + 17617920);
  int* offsets = (int*)(ws + 51200000);
  int* counts = (int*)(ws + 51600128);
  unsigned* cpack = (unsigned*)(ws + 52000128);
  int* bsum = (int*)(ws + 58400128);
  int* bpre = (int*)(ws + 58400640);
  uint4* wpack = (uint4*)(ws + 58401152);

  k_cvt<<<6250, 256, 0, stream>>>(emb, (uint4*)tbl, mbcur);
  k_bscatter2<<<PBLK, PTHR, 0, stream>>>(erow, ecol, eva, mbcur, ebuf);
  k_hist<<<64, 1024, 0, stream>>>(ebuf, mbcur, partial);
  k_sum<<<(NN + 255) / 256, 256, 0, stream>>>(partial, counts);
  k_scan1<<<NBLK, 1024, 0, stream>>>(counts, offsets, bsum);
  k_scan2<<<1, 64, 0, stream>>>(bsum, bpre);
  k_scan3<<<NBLK, 1024, 0, stream>>>(offsets, bpre);
  k_scatter3<<<64, 1024, 0, stream>>>(ebuf, mbcur, partial, offsets, cpack);
  k_packw<<<16, 256, 0, stream>>>(W1, W2, wpack);
  k_spmm<<<NN / 4, 256, 0, stream>>>(offsets, cpack, tbl, (unsigned*)rel);
  k_phase2<<<(NN + 127) / 128, 256, 0, stream>>>(rel, tbl, wpack, out);
}